// Round 10
// baseline (259.093 us; speedup 1.0000x reference)
//
#include <hip/hip_runtime.h>

#define S_LEN 2048
#define D_MODEL 1024
#define DH 64      // head dim
#define BQ 64      // q rows per block
#define BK 64      // keys per k-tile
#define LDK 72     // padded LDS row strides (+8 elems, 16B-aligned rows, 2-way max conflict)
#define LDV 72
#define LDP 72

using short8 = __attribute__((ext_vector_type(8))) short;  // 8 bf16 (4 VGPRs)
using f32x4  = __attribute__((ext_vector_type(4))) float;

__device__ __forceinline__ unsigned short f2bf(float x) {
    union { float f; unsigned int u; } c; c.f = x;
    unsigned int u = c.u;
    u += 0x7fffu + ((u >> 16) & 1u);   // RNE
    return (unsigned short)(u >> 16);
}

__global__ __launch_bounds__(256) void mha_fwd(
    const float* __restrict__ Q,
    const float* __restrict__ K,
    const float* __restrict__ V,
    const int* __restrict__ M,
    float* __restrict__ O)
{
    __shared__ unsigned short Ks[BK][LDK];      // K-tile (bf16), row-major [key][d]
    __shared__ unsigned short Vt[DH][LDV];      // V-tile (bf16) transposed [d][key]
    __shared__ unsigned short Ps[4][16][LDP];   // per-wave P scratch (bf16) [qrow][key]

    const int blk = blockIdx.x;
    const int b   = blk >> 9;           // 512 blocks per batch
    const int h   = (blk >> 5) & 15;
    const int qt  = blk & 31;
    const int qbase = qt * BQ;

    const int tid  = threadIdx.x;
    const int wave = tid >> 6;
    const int lane = tid & 63;
    const int n16  = lane & 15;
    const int quad = lane >> 4;

    // --- Q fragments (A operand): A[m=lane&15][k=quad*8+j]; f32 loads, bf16 RNE ---
    const size_t qoff = (size_t)(b * S_LEN + qbase + wave * 16 + n16) * D_MODEL + h * DH + quad * 8;
    short8 qf0, qf1;
    {
        f32x4 a0 = *(const f32x4*)(Q + qoff);
        f32x4 a1 = *(const f32x4*)(Q + qoff + 4);
        f32x4 a2 = *(const f32x4*)(Q + qoff + 32);
        f32x4 a3 = *(const f32x4*)(Q + qoff + 36);
        #pragma unroll
        for (int j = 0; j < 4; ++j) {
            qf0[j]     = (short)f2bf(a0[j]);
            qf0[4 + j] = (short)f2bf(a1[j]);
            qf1[j]     = (short)f2bf(a2[j]);
            qf1[4 + j] = (short)f2bf(a3[j]);
        }
    }

    f32x4 o0 = {0.f,0.f,0.f,0.f}, o1 = o0, o2 = o0, o3 = o0;
    float mrow[4] = {-INFINITY,-INFINITY,-INFINITY,-INFINITY};
    float lrow[4] = {0.f,0.f,0.f,0.f};

    // C/D layout rows: qbase + wave*16 + quad*4 + r ; col = lane&15
    const size_t mbase0 = ((size_t)(b * S_LEN + qbase + wave * 16 + quad * 4)) * S_LEN;

    for (int kb = 0; kb < S_LEN; kb += BK) {
        __syncthreads();   // protect LDS staging vs previous iteration's readers
        // ---- stage K tile: Ks[key][d]; 32B f32 loads -> bf16 -> 16B LDS stores ----
        {
            int seg = tid;                       // 512 segments of 8 elems
            #pragma unroll
            for (int it = 0; it < 2; ++it, seg += 256) {
                int row = seg >> 3, c8 = (seg & 7) << 3;
                const float* kp = K + (size_t)(b * S_LEN + kb + row) * D_MODEL + h * DH + c8;
                f32x4 p0 = *(const f32x4*)kp;
                f32x4 p1 = *(const f32x4*)(kp + 4);
                short8 w;
                #pragma unroll
                for (int j = 0; j < 4; ++j) {
                    w[j]     = (short)f2bf(p0[j]);
                    w[4 + j] = (short)f2bf(p1[j]);
                }
                *(short8*)&Ks[row][c8] = w;
            }
        }
        // ---- stage V transposed: Vt[d][key]; lane-coalesced f32 loads ----
        {
            int d = tid & 63, kg = tid >> 6;     // 4 key-groups of 16
            unsigned short tmp[16];
            #pragma unroll
            for (int kk = 0; kk < 16; ++kk)
                tmp[kk] = f2bf(V[(size_t)(b * S_LEN + kb + kg * 16 + kk) * D_MODEL + h * DH + d]);
            *(short8*)&Vt[d][kg * 16]     = *(const short8*)&tmp[0];
            *(short8*)&Vt[d][kg * 16 + 8] = *(const short8*)&tmp[8];
        }
        __syncthreads();

        // ---- QK^T: 4 col-tiles x (d=64 -> 2 mfma) ----
        f32x4 s[4];
        #pragma unroll
        for (int ct = 0; ct < 4; ++ct) {
            short8 kf0 = *(const short8*)&Ks[ct * 16 + n16][     quad * 8];
            short8 kf1 = *(const short8*)&Ks[ct * 16 + n16][32 + quad * 8];
            f32x4 acc = {0.f,0.f,0.f,0.f};
            acc = __builtin_amdgcn_mfma_f32_16x16x32_bf16(qf0, kf0, acc, 0, 0, 0);
            acc = __builtin_amdgcn_mfma_f32_16x16x32_bf16(qf1, kf1, acc, 0, 0, 0);
            s[ct] = acc;
        }
        // ---- scale + additive mask bias ----
        #pragma unroll
        for (int ct = 0; ct < 4; ++ct) {
            #pragma unroll
            for (int r = 0; r < 4; ++r) {
                int mk = M[mbase0 + (size_t)r * S_LEN + kb + ct * 16 + n16];
                float bias = mk ? 0.f : -1.0e9f;
                s[ct][r] = fmaf(s[ct][r], 0.125f, bias);   // 1/sqrt(64)
            }
        }
        // ---- online softmax: row max / alpha ----
        float al[4];
        #pragma unroll
        for (int r = 0; r < 4; ++r) {
            float v = fmaxf(fmaxf(s[0][r], s[1][r]), fmaxf(s[2][r], s[3][r]));
            v = fmaxf(v, __shfl_xor(v, 1));
            v = fmaxf(v, __shfl_xor(v, 2));
            v = fmaxf(v, __shfl_xor(v, 4));
            v = fmaxf(v, __shfl_xor(v, 8));
            float mn = fmaxf(mrow[r], v);
            al[r] = exp2f((mrow[r] - mn) * 1.44269504f);
            mrow[r] = mn;
        }
        // ---- p = exp(s - m), row sums ----
        float ts[4] = {0.f,0.f,0.f,0.f};
        #pragma unroll
        for (int ct = 0; ct < 4; ++ct) {
            #pragma unroll
            for (int r = 0; r < 4; ++r) {
                float p = exp2f((s[ct][r] - mrow[r]) * 1.44269504f);
                s[ct][r] = p;
                ts[r] += p;
            }
        }
        #pragma unroll
        for (int r = 0; r < 4; ++r) {
            float v = ts[r];
            v += __shfl_xor(v, 1);
            v += __shfl_xor(v, 2);
            v += __shfl_xor(v, 4);
            v += __shfl_xor(v, 8);
            lrow[r] = lrow[r] * al[r] + v;
        }
        // ---- rescale O accumulator ----
        #pragma unroll
        for (int r = 0; r < 4; ++r) { o0[r] *= al[r]; o1[r] *= al[r]; o2[r] *= al[r]; o3[r] *= al[r]; }
        // ---- P (C-layout) -> LDS (A-layout rows); same-wave produce/consume, DS in-order ----
        #pragma unroll
        for (int ct = 0; ct < 4; ++ct) {
            #pragma unroll
            for (int r = 0; r < 4; ++r)
                Ps[wave][quad * 4 + r][ct * 16 + n16] = f2bf(s[ct][r]);
        }
        // ---- PV: O[16q x 64d] += P[16q x 64k] * V[64k x 64d] ----
        #pragma unroll
        for (int kc = 0; kc < 2; ++kc) {
            short8 af = *(const short8*)&Ps[wave][n16][kc * 32 + quad * 8];
            short8 b0 = *(const short8*)&Vt[      n16][kc * 32 + quad * 8];
            short8 b1 = *(const short8*)&Vt[16 + n16][kc * 32 + quad * 8];
            short8 b2 = *(const short8*)&Vt[32 + n16][kc * 32 + quad * 8];
            short8 b3 = *(const short8*)&Vt[48 + n16][kc * 32 + quad * 8];
            o0 = __builtin_amdgcn_mfma_f32_16x16x32_bf16(af, b0, o0, 0, 0, 0);
            o1 = __builtin_amdgcn_mfma_f32_16x16x32_bf16(af, b1, o1, 0, 0, 0);
            o2 = __builtin_amdgcn_mfma_f32_16x16x32_bf16(af, b2, o2, 0, 0, 0);
            o3 = __builtin_amdgcn_mfma_f32_16x16x32_bf16(af, b3, o3, 0, 0, 0);
        }
    }

    // ---- epilogue: normalize, store f32 (reference output dtype) ----
    #pragma unroll
    for (int r = 0; r < 4; ++r) {
        float rl = 1.f / lrow[r];
        size_t row = (size_t)(b * S_LEN + qbase + wave * 16 + quad * 4 + r);
        float* op = O + row * D_MODEL + h * DH + n16;
        op[0]  = o0[r] * rl;
        op[16] = o1[r] * rl;
        op[32] = o2[r] * rl;
        op[48] = o3[r] * rl;
    }
}

extern "C" void kernel_launch(void* const* d_in, const int* in_sizes, int n_in,
                              void* d_out, int out_size, void* d_ws, size_t ws_size,
                              hipStream_t stream) {
    const float* Q = (const float*)d_in[0];
    const float* K = (const float*)d_in[1];
    const float* V = (const float*)d_in[2];
    const int*   M = (const int*)d_in[3];
    float*       O = (float*)d_out;
    dim3 grid(2 * 16 * 32), block(256);
    hipLaunchKernelGGL(mha_fwd, grid, block, 0, stream, Q, K, V, M, O);
}